// Round 16
// baseline (571.163 us; speedup 1.0000x reference)
//
#include <hip/hip_runtime.h>
#include <hip/hip_bf16.h>

#define T_DIM 4096
#define B_DIM 32
#define I_DIM 512
#define O_DIM 512
#define M_DIM (T_DIM * B_DIM)   // 131072
#define PARAM 0.1f
#define ISCALE 1.1111112f       // 1/(1-p)

#define STRIP 32
#define TAPS 8                  // p^8 = 1e-8 << bf16 eps

typedef __attribute__((ext_vector_type(8))) short bf16x8;
typedef __attribute__((ext_vector_type(4))) float f32x4;

__device__ __forceinline__ unsigned short f2bf(float f) {
    union { __hip_bfloat16 b; unsigned short u; } cv;
    cv.b = __float2bfloat16(f);
    return cv.u;
}

// --- W fp32 -> bf16 (0.5 MB, ws offset 0) ---
__global__ __launch_bounds__(256) void wcvt_kernel(const float* __restrict__ W,
                                                   unsigned short* __restrict__ Wb) {
    const int i = (blockIdx.x * 256 + threadIdx.x) * 4;
    f32x4 v = *(const f32x4*)(W + i);
    ushort4 o;
    o.x = f2bf(v[0]); o.y = f2bf(v[1]); o.z = f2bf(v[2]); o.w = f2bf(v[3]);
    *(ushort4*)(Wb + i) = o;
}

// --- EMA over raw X (linearity: EMA(XW+b) = EMA(X)W + s[t]*b). Strip-parallel,
// TAPS warm-up reads raw X; bf16 output compacted into d_ws. ---
__global__ __launch_bounds__(256) void xema_kernel(const float* __restrict__ X,
                                                   unsigned short* __restrict__ Xv) {
    const int s   = blockIdx.x >> 4;                 // strip 0..127
    const int blk = blockIdx.x & 15;
    const int col = (blk * 256 + threadIdx.x) * 4;
    const int t0  = s * STRIP;
    const int b   = col >> 9;
    const int o   = col & 511;

    const float* xin = X + (size_t)t0 * 16384 + col;
    unsigned short* xout = Xv + (size_t)(t0 * 32 + b) * 512 + o;

    f32x4 v = {0.f, 0.f, 0.f, 0.f};
    if (s > 0) {
        const float* w = xin - (size_t)TAPS * 16384;
        #pragma unroll
        for (int j = 0; j < TAPS; ++j)
            v = PARAM * v + *(const f32x4*)(w + (size_t)j * 16384);
    }

    f32x4 bufA[4], bufB[4];
    #pragma unroll
    for (int j = 0; j < 4; ++j) bufA[j] = *(const f32x4*)(xin + (size_t)j * 16384);

    #pragma unroll
    for (int i = 0; i < STRIP; i += 8) {
        #pragma unroll
        for (int j = 0; j < 4; ++j)
            bufB[j] = *(const f32x4*)(xin + (size_t)(i + 4 + j) * 16384);
        #pragma unroll
        for (int j = 0; j < 4; ++j) {
            v = PARAM * v + bufA[j];
            ushort4 pk; pk.x = f2bf(v[0]); pk.y = f2bf(v[1]); pk.z = f2bf(v[2]); pk.w = f2bf(v[3]);
            *(ushort4*)(xout + (size_t)(i + j) * 16384) = pk;
        }
        if (i + 8 < STRIP) {
            #pragma unroll
            for (int j = 0; j < 4; ++j)
                bufA[j] = *(const f32x4*)(xin + (size_t)(i + 8 + j) * 16384);
        }
        #pragma unroll
        for (int j = 0; j < 4; ++j) {
            v = PARAM * v + bufB[j];
            ushort4 pk; pk.x = f2bf(v[0]); pk.y = f2bf(v[1]); pk.z = f2bf(v[2]); pk.w = f2bf(v[3]);
            *(ushort4*)(xout + (size_t)(i + 4 + j) * 16384) = pk;
        }
    }
}

// --- GEMM: B-in-registers, barrier-free, zero LDS. Each wave holds its 16
// W-cols x K=512 as 16 persistent bf16x8 (64 VGPR), loaded once from L2-hot
// Wb. Block = 4 waves x 16 cols = 64 cols; all waves share the same 64-row A
// chunk (identical addresses -> L1 broadcast); block marches 8 chunks of 64
// rows. Per step: 4 A-frag global loads (depth-2, PINNED with sched_barrier(0)
// so hipcc cannot sink them — R15's rematerialization failure) + 4 MFMA
// (swapped operands -> Y^T frag -> float4 stores). Stores overlap next chunk.
// XCD map: 8 col-groups x 32 row-blocks per XCD; per-XCD A working set tiny. ---
__global__ __launch_bounds__(256) void gemm_kernel(const unsigned short* __restrict__ Xv,
                                                   const unsigned short* __restrict__ Wb,
                                                   const float* __restrict__ bias,
                                                   float* __restrict__ Y) {
    const int tid  = threadIdx.x;
    const int lane = tid & 63;
    const int wave = tid >> 6;               // 0..3

    const int xcd  = blockIdx.x & 7;
    const int idx  = blockIdx.x >> 3;        // 0..255
    const int colg = idx & 7;                // inner: 8 col-groups share rows
    const int rowb = idx >> 3;               // 0..31 row-blocks per XCD
    const int col0 = colg * 64 + wave * 16;  // this wave's 16 cols
    const int rowBase = (xcd * 32 + rowb) * 512;   // block's 512-row span

    // Persistent B fragments: s = ks*2+kk, frag = W[col0+(lane&15)][k..k+7].
    const unsigned short* bBase =
        Wb + (size_t)(col0 + (lane & 15)) * 512 + ((lane >> 4) << 3);
    bf16x8 bfr[16];
    #pragma unroll
    for (int s = 0; s < 16; ++s)
        bfr[s] = *(const bf16x8*)(bBase + (s >> 1) * 64 + (s & 1) * 32);

    const f32x4 bvv = *(const f32x4*)(bias + col0 + ((lane >> 4) << 2));

    const unsigned short* aRow =
        Xv + (size_t)(rowBase + (lane & 15)) * 512 + ((lane >> 4) << 3);

    // Depth-2 A prefetch: 3 rotating buffers, all indices literal after unroll.
    bf16x8 ap[3][4];
    #define LOADA(st)                                                                 \
        do { if ((st) < 128) {                                                        \
            _Pragma("unroll")                                                         \
            for (int mf = 0; mf < 4; ++mf)                                            \
                ap[(st) % 3][mf] = *(const bf16x8*)(aRow +                            \
                    (size_t)(((st) >> 4) * 64 + mf * 16) * 512 +                      \
                    ((((st) & 15)) >> 1) * 64 + ((st) & 1) * 32);                     \
        } } while (0)

    LOADA(0);
    LOADA(1);
    __builtin_amdgcn_sched_barrier(0);

    #pragma unroll
    for (int ch = 0; ch < 8; ++ch) {
        f32x4 acc[4] = {};
        #pragma unroll
        for (int s = 0; s < 16; ++s) {
            const int st = ch * 16 + s;
            LOADA(st + 2);                        // issue 2 steps ahead
            __builtin_amdgcn_sched_barrier(0);    // pin: loads stay ABOVE the MFMAs
            #pragma unroll
            for (int mf = 0; mf < 4; ++mf)
                acc[mf] = __builtin_amdgcn_mfma_f32_16x16x32_bf16(
                    bfr[s], ap[st % 3][mf], acc[mf], 0, 0, 0);   // swapped -> Y^T
            __builtin_amdgcn_sched_barrier(0);
        }
        // Chunk epilogue: Y = acc + s[t]*bias, float4 stores (overlap next chunk).
        const int rowc = rowBase + ch * 64;
        float sc2[2];
        #pragma unroll
        for (int tt = 0; tt < 2; ++tt)
            sc2[tt] = (1.0f - __expf(-2.3025851f * (float)((rowc >> 5) + tt + 1))) * ISCALE;
        #pragma unroll
        for (int mf = 0; mf < 4; ++mf) {
            const int grow = rowc + mf * 16 + (lane & 15);
            f32x4 out;
            #pragma unroll
            for (int e = 0; e < 4; ++e) out[e] = acc[mf][e] + sc2[mf >> 1] * bvv[e];
            *(f32x4*)(Y + (size_t)grow * O_DIM + col0 + ((lane >> 4) << 2)) = out;
        }
    }
    #undef LOADA
}

extern "C" void kernel_launch(void* const* d_in, const int* in_sizes, int n_in,
                              void* d_out, int out_size, void* d_ws, size_t ws_size,
                              hipStream_t stream) {
    const float* X    = (const float*)d_in[0];
    const float* W    = (const float*)d_in[1];
    const float* bias = (const float*)d_in[2];
    float* Y = (float*)d_out;
    unsigned short* Wb = (unsigned short*)d_ws;                       // 512 KB
    unsigned short* Xv = (unsigned short*)((char*)d_ws + (1 << 20));  // 134 MB

    wcvt_kernel<<<dim3(O_DIM * I_DIM / (256 * 4)), dim3(256), 0, stream>>>(W, Wb);
    xema_kernel<<<dim3((T_DIM / STRIP) * 16), dim3(256), 0, stream>>>(X, Xv);
    gemm_kernel<<<dim3(2048), dim3(256), 0, stream>>>(Xv, Wb, bias, Y);
}

// Round 17
// 251.240 us; speedup vs baseline: 2.2734x; 2.2734x over previous
//
#include <hip/hip_runtime.h>
#include <hip/hip_bf16.h>

#define T_DIM 4096
#define B_DIM 32
#define I_DIM 512
#define O_DIM 512
#define M_DIM (T_DIM * B_DIM)   // 131072
#define PARAM 0.1f
#define ISCALE 1.1111112f       // 1/(1-p)

#define STRIP 32
#define TAPS 8                  // p^8 = 1e-8 << bf16 eps

#define BM 256
#define BN 256
#define BK 64
#define NK (I_DIM / BK)         // 8

typedef __attribute__((ext_vector_type(8))) short bf16x8;
typedef __attribute__((ext_vector_type(4))) float f32x4;

__device__ __forceinline__ unsigned short f2bf(float f) {
    union { __hip_bfloat16 b; unsigned short u; } cv;
    cv.b = __float2bfloat16(f);
    return cv.u;
}

// --- W fp32 -> bf16 (0.5 MB, ws offset 0) ---
__global__ __launch_bounds__(256) void wcvt_kernel(const float* __restrict__ W,
                                                   unsigned short* __restrict__ Wb) {
    const int i = (blockIdx.x * 256 + threadIdx.x) * 4;
    f32x4 v = *(const f32x4*)(W + i);
    ushort4 o;
    o.x = f2bf(v[0]); o.y = f2bf(v[1]); o.z = f2bf(v[2]); o.w = f2bf(v[3]);
    *(ushort4*)(Wb + i) = o;
}

// --- EMA over raw X (linearity: EMA(XW+b) = EMA(X)W + s[t]*b). Strip-parallel,
// TAPS warm-up reads raw X; bf16 output compacted into d_ws. At roofline. ---
__global__ __launch_bounds__(256) void xema_kernel(const float* __restrict__ X,
                                                   unsigned short* __restrict__ Xv) {
    const int s   = blockIdx.x >> 4;                 // strip 0..127
    const int blk = blockIdx.x & 15;
    const int col = (blk * 256 + threadIdx.x) * 4;
    const int t0  = s * STRIP;
    const int b   = col >> 9;
    const int o   = col & 511;

    const float* xin = X + (size_t)t0 * 16384 + col;
    unsigned short* xout = Xv + (size_t)(t0 * 32 + b) * 512 + o;

    f32x4 v = {0.f, 0.f, 0.f, 0.f};
    if (s > 0) {
        const float* w = xin - (size_t)TAPS * 16384;
        #pragma unroll
        for (int j = 0; j < TAPS; ++j)
            v = PARAM * v + *(const f32x4*)(w + (size_t)j * 16384);
    }

    f32x4 bufA[4], bufB[4];
    #pragma unroll
    for (int j = 0; j < 4; ++j) bufA[j] = *(const f32x4*)(xin + (size_t)j * 16384);

    #pragma unroll
    for (int i = 0; i < STRIP; i += 8) {
        #pragma unroll
        for (int j = 0; j < 4; ++j)
            bufB[j] = *(const f32x4*)(xin + (size_t)(i + 4 + j) * 16384);
        #pragma unroll
        for (int j = 0; j < 4; ++j) {
            v = PARAM * v + bufA[j];
            ushort4 pk; pk.x = f2bf(v[0]); pk.y = f2bf(v[1]); pk.z = f2bf(v[2]); pk.w = f2bf(v[3]);
            *(ushort4*)(xout + (size_t)(i + j) * 16384) = pk;
        }
        if (i + 8 < STRIP) {
            #pragma unroll
            for (int j = 0; j < 4; ++j)
                bufA[j] = *(const f32x4*)(xin + (size_t)(i + 8 + j) * 16384);
        }
        #pragma unroll
        for (int j = 0; j < 4; ++j) {
            v = PARAM * v + bufB[j];
            ushort4 pk; pk.x = f2bf(v[0]); pk.y = f2bf(v[1]); pk.z = f2bf(v[2]); pk.w = f2bf(v[3]);
            *(ushort4*)(xout + (size_t)(i + 4 + j) * 16384) = pk;
        }
    }
}

// --- GEMM: 256x256 tile, simple 2-barrier loop (R13 components, 4x the
// per-block MFMA work). 512 thr / 8 waves (2 wm x 4 wn), wave-tile 128x64,
// acc 8x4. Single-buffer 64KB LDS -> 2 blocks/CU. Pre-swizzled gload_lds
// staging (involution c^(r&7), 8 loads/thr/step); conflict-free swizzled
// ds_read; swapped-operand MFMA -> Y^T frags -> float4 epilogue. Staged L2
// traffic 536MB (half of R13). XCD grouping: bn-pair adjacent per XCD. ---
__global__ __launch_bounds__(512, 2) void gemm_kernel(const unsigned short* __restrict__ Xv,
                                                      const unsigned short* __restrict__ Wb,
                                                      const float* __restrict__ bias,
                                                      float* __restrict__ Y) {
    __shared__ __align__(16) short As[BM * BK];   // 32 KB
    __shared__ __align__(16) short Bs[BN * BK];   // 32 KB

    const int tid  = threadIdx.x;
    const int lane = tid & 63;
    const int wave = tid >> 6;        // 0..7
    const int wm   = wave >> 2;       // 0..1 (128-row half)
    const int wn   = wave & 3;        // 0..3 (64-col quarter)

    // 1024 blocks (%8==0): xcd = bid&7; bn toggles fastest within an XCD chunk.
    const int bid  = blockIdx.x;
    const int swz  = (bid & 7) * 128 + (bid >> 3);
    const int bn   = swz & 1;
    const int mt   = swz >> 1;                    // 0..511
    const int row0 = mt * BM;
    const int col0 = bn * BN;

    // Staging: 16B chunks, 8 per 128B row; 4 row-sets of 64. r&7 = (tid>>3)&7
    // for every set -> swizzled source chunk cs is per-thread constant.
    const int cs = (tid & 7) ^ ((tid >> 3) & 7);
    const unsigned short* aSrc = Xv + (size_t)(row0 + (tid >> 3)) * 512 + cs * 8;
    const unsigned short* bSrc = Wb + (size_t)(col0 + (tid >> 3)) * 512 + cs * 8;

    f32x4 acc[8][4] = {};   // [mf][nf], swapped-operand: reg j = 4 consecutive Y-cols

    for (int ks = 0; ks < NK; ++ks) {
        const int k0 = ks * BK;
        #pragma unroll
        for (int s_ = 0; s_ < 4; ++s_)
            __builtin_amdgcn_global_load_lds(
                (const __attribute__((address_space(1))) unsigned int*)(aSrc + (size_t)s_ * 64 * 512 + k0),
                (__attribute__((address_space(3))) unsigned int*)(As + (s_ * 512 + tid) * 8),
                16, 0, 0);
        #pragma unroll
        for (int s_ = 0; s_ < 4; ++s_)
            __builtin_amdgcn_global_load_lds(
                (const __attribute__((address_space(1))) unsigned int*)(bSrc + (size_t)s_ * 64 * 512 + k0),
                (__attribute__((address_space(3))) unsigned int*)(Bs + (s_ * 512 + tid) * 8),
                16, 0, 0);
        __syncthreads();

        #pragma unroll
        for (int kk = 0; kk < 2; ++kk) {
            const int cc = kk * 4 + (lane >> 4);
            bf16x8 a_[8], b_[4];
            #pragma unroll
            for (int mf = 0; mf < 8; ++mf) {
                const int r = wm * 128 + mf * 16 + (lane & 15);
                a_[mf] = *(const bf16x8*)((const char*)As + r * 128 + ((cc ^ (r & 7)) << 4));
            }
            #pragma unroll
            for (int nf = 0; nf < 4; ++nf) {
                const int r = wn * 64 + nf * 16 + (lane & 15);
                b_[nf] = *(const bf16x8*)((const char*)Bs + r * 128 + ((cc ^ (r & 7)) << 4));
            }
            #pragma unroll
            for (int mf = 0; mf < 8; ++mf)
                #pragma unroll
                for (int nf = 0; nf < 4; ++nf)
                    acc[mf][nf] = __builtin_amdgcn_mfma_f32_16x16x32_bf16(
                        b_[nf], a_[mf], acc[mf][nf], 0, 0, 0);   // swapped -> Y^T frag
        }
        __syncthreads();
    }

    // Epilogue: Y = acc + s[t]*bias, float4 stores. t = grow>>5; within the
    // 128-row wave tile, t offset = mf>>1 (mf*16+(lane&15) < (mf>>1)*32+32).
    float sc4[4];
    #pragma unroll
    for (int tt = 0; tt < 4; ++tt) {
        const int t_ = ((row0 + wm * 128) >> 5) + tt;
        sc4[tt] = (1.0f - __expf(-2.3025851f * (float)(t_ + 1))) * ISCALE;
    }
    f32x4 bvv[4];
    #pragma unroll
    for (int nf = 0; nf < 4; ++nf)
        bvv[nf] = *(const f32x4*)(bias + col0 + wn * 64 + nf * 16 + ((lane >> 4) << 2));

    #pragma unroll
    for (int mf = 0; mf < 8; ++mf) {
        const int grow = row0 + wm * 128 + mf * 16 + (lane & 15);
        const float sc = sc4[mf >> 1];
        #pragma unroll
        for (int nf = 0; nf < 4; ++nf) {
            const int gcol = col0 + wn * 64 + nf * 16 + ((lane >> 4) << 2);
            f32x4 out;
            #pragma unroll
            for (int e = 0; e < 4; ++e) out[e] = acc[mf][nf][e] + sc * bvv[nf][e];
            *(f32x4*)(Y + (size_t)grow * O_DIM + gcol) = out;
        }
    }
}

extern "C" void kernel_launch(void* const* d_in, const int* in_sizes, int n_in,
                              void* d_out, int out_size, void* d_ws, size_t ws_size,
                              hipStream_t stream) {
    const float* X    = (const float*)d_in[0];
    const float* W    = (const float*)d_in[1];
    const float* bias = (const float*)d_in[2];
    float* Y = (float*)d_out;
    unsigned short* Wb = (unsigned short*)d_ws;                       // 512 KB
    unsigned short* Xv = (unsigned short*)((char*)d_ws + (1 << 20));  // 134 MB

    wcvt_kernel<<<dim3(O_DIM * I_DIM / (256 * 4)), dim3(256), 0, stream>>>(W, Wb);
    xema_kernel<<<dim3((T_DIM / STRIP) * 16), dim3(256), 0, stream>>>(X, Xv);
    gemm_kernel<<<dim3((M_DIM / BM) * (O_DIM / BN)), dim3(512), 0, stream>>>(Xv, Wb, bias, Y);
}

// Round 18
// 232.267 us; speedup vs baseline: 2.4591x; 1.0817x over previous
//
#include <hip/hip_runtime.h>
#include <hip/hip_bf16.h>

#define T_DIM 4096
#define B_DIM 32
#define I_DIM 512
#define O_DIM 512
#define M_DIM (T_DIM * B_DIM)   // 131072
#define PARAM 0.1f
#define ISCALE 1.1111112f       // 1/(1-p)

#define STRIP 32
#define TAPS 8                  // p^8 = 1e-8 << bf16 eps

#define BM 128
#define BN 128
#define BK 64
#define NK (I_DIM / BK)         // 8

typedef __attribute__((ext_vector_type(8))) short bf16x8;
typedef __attribute__((ext_vector_type(4))) float f32x4;

__device__ __forceinline__ unsigned short f2bf(float f) {
    union { __hip_bfloat16 b; unsigned short u; } cv;
    cv.b = __float2bfloat16(f);
    return cv.u;
}

// --- W fp32 -> bf16 (0.5 MB, ws offset 0) ---
__global__ __launch_bounds__(256) void wcvt_kernel(const float* __restrict__ W,
                                                   unsigned short* __restrict__ Wb) {
    const int i = (blockIdx.x * 256 + threadIdx.x) * 4;
    f32x4 v = *(const f32x4*)(W + i);
    ushort4 o;
    o.x = f2bf(v[0]); o.y = f2bf(v[1]); o.z = f2bf(v[2]); o.w = f2bf(v[3]);
    *(ushort4*)(Wb + i) = o;
}

// --- EMA over raw X (linearity: EMA(XW+b) = EMA(X)W + s[t]*b). Strip-parallel,
// TAPS warm-up reads raw X; bf16 output compacted into d_ws. Near roofline. ---
__global__ __launch_bounds__(256) void xema_kernel(const float* __restrict__ X,
                                                   unsigned short* __restrict__ Xv) {
    const int s   = blockIdx.x >> 4;                 // strip 0..127
    const int blk = blockIdx.x & 15;
    const int col = (blk * 256 + threadIdx.x) * 4;
    const int t0  = s * STRIP;
    const int b   = col >> 9;
    const int o   = col & 511;

    const float* xin = X + (size_t)t0 * 16384 + col;
    unsigned short* xout = Xv + (size_t)(t0 * 32 + b) * 512 + o;

    f32x4 v = {0.f, 0.f, 0.f, 0.f};
    if (s > 0) {
        const float* w = xin - (size_t)TAPS * 16384;
        #pragma unroll
        for (int j = 0; j < TAPS; ++j)
            v = PARAM * v + *(const f32x4*)(w + (size_t)j * 16384);
    }

    f32x4 bufA[4], bufB[4];
    #pragma unroll
    for (int j = 0; j < 4; ++j) bufA[j] = *(const f32x4*)(xin + (size_t)j * 16384);

    #pragma unroll
    for (int i = 0; i < STRIP; i += 8) {
        #pragma unroll
        for (int j = 0; j < 4; ++j)
            bufB[j] = *(const f32x4*)(xin + (size_t)(i + 4 + j) * 16384);
        #pragma unroll
        for (int j = 0; j < 4; ++j) {
            v = PARAM * v + bufA[j];
            ushort4 pk; pk.x = f2bf(v[0]); pk.y = f2bf(v[1]); pk.z = f2bf(v[2]); pk.w = f2bf(v[3]);
            *(ushort4*)(xout + (size_t)(i + j) * 16384) = pk;
        }
        if (i + 8 < STRIP) {
            #pragma unroll
            for (int j = 0; j < 4; ++j)
                bufA[j] = *(const f32x4*)(xin + (size_t)(i + 8 + j) * 16384);
        }
        #pragma unroll
        for (int j = 0; j < 4; ++j) {
            v = PARAM * v + bufB[j];
            ushort4 pk; pk.x = f2bf(v[0]); pk.y = f2bf(v[1]); pk.z = f2bf(v[2]); pk.w = f2bf(v[3]);
            *(ushort4*)(xout + (size_t)(i + 4 + j) * 16384) = pk;
        }
    }
}

// --- GEMM: R13 (best) + ENTRY STAGGER. Structure: m97 replica, 256 thr /
// 4 waves, 128x128 tile, BK=64, wave-tile 64x64, single-buffer 32KB LDS ->
// 4 blocks/CU; pre-swizzled gload_lds staging; conflict-free swizzled ds_read;
// swapped-operand MFMA -> Y^T frags -> float4 epilogue.
// NEW: co-resident blocks (raw bid differing by 256 share a CU at 4 blk/CU)
// sleep 0/512/1024/1536 cy at entry -> their stage/drain/compute phases
// interleave instead of phase-locking (m114 overlap needs phase offset; 8-step
// loops never drift apart on their own — the hypothesis for the 6x-vs-m97
// per-step gap). Cost if wrong: <=0.7us once per block. ---
__global__ __launch_bounds__(256, 4) void gemm_kernel(const unsigned short* __restrict__ Xv,
                                                      const unsigned short* __restrict__ Wb,
                                                      const float* __restrict__ bias,
                                                      float* __restrict__ Y) {
    __shared__ __align__(16) short As[BM * BK];   // 16 KB
    __shared__ __align__(16) short Bs[BN * BK];   // 16 KB

    // Phase stagger: blocks landing on the same CU get different start offsets.
    switch ((blockIdx.x >> 8) & 3) {
        case 1: __builtin_amdgcn_s_sleep(8);  break;   // ~512 cy
        case 2: __builtin_amdgcn_s_sleep(16); break;   // ~1024 cy
        case 3: __builtin_amdgcn_s_sleep(24); break;   // ~1536 cy
        default: break;
    }

    const int tid  = threadIdx.x;
    const int lane = tid & 63;
    const int wave = tid >> 6;        // 0..3
    const int wm   = wave >> 1;       // 0..1
    const int wn   = wave & 1;        // 0..1

    // 4096 blocks: xcd = bid&7; all 4 bn of one mt run temporally close on one
    // XCD -> A panel HBM-fetched once, L2-served 4x; W (512KB) stays L2-hot.
    const int bid = blockIdx.x;
    const int j   = bid >> 3;                     // 0..511
    const int bn  = j & 3;
    const int mt  = (bid & 7) * 128 + (j >> 2);   // 0..1023
    const int row0 = mt * BM;
    const int col0 = bn * BN;

    // Staging: 16B chunks, 8 per 128B row; 4 sets of 32 rows. r&7 = (tid>>3)&7
    // for every set -> swizzled source chunk cs is per-thread constant.
    const int cs = (tid & 7) ^ ((tid >> 3) & 7);
    const unsigned short* aSrc = Xv + (size_t)(row0 + (tid >> 3)) * 512 + cs * 8;
    const unsigned short* bSrc = Wb + (size_t)(col0 + (tid >> 3)) * 512 + cs * 8;

    f32x4 acc[4][4] = {};   // [mf][nf], swapped-operand: reg j = 4 consecutive Y-cols

    for (int ks = 0; ks < NK; ++ks) {
        const int k0 = ks * BK;
        #pragma unroll
        for (int s_ = 0; s_ < 4; ++s_)
            __builtin_amdgcn_global_load_lds(
                (const __attribute__((address_space(1))) unsigned int*)(aSrc + (size_t)s_ * 32 * 512 + k0),
                (__attribute__((address_space(3))) unsigned int*)(As + (s_ * 256 + tid) * 8),
                16, 0, 0);
        #pragma unroll
        for (int s_ = 0; s_ < 4; ++s_)
            __builtin_amdgcn_global_load_lds(
                (const __attribute__((address_space(1))) unsigned int*)(bSrc + (size_t)s_ * 32 * 512 + k0),
                (__attribute__((address_space(3))) unsigned int*)(Bs + (s_ * 256 + tid) * 8),
                16, 0, 0);
        __syncthreads();

        #pragma unroll
        for (int kk = 0; kk < 2; ++kk) {
            const int cc = kk * 4 + (lane >> 4);
            bf16x8 a_[4], b_[4];
            #pragma unroll
            for (int mf = 0; mf < 4; ++mf) {
                const int r = wm * 64 + mf * 16 + (lane & 15);
                a_[mf] = *(const bf16x8*)((const char*)As + r * 128 + ((cc ^ (r & 7)) << 4));
            }
            #pragma unroll
            for (int nf = 0; nf < 4; ++nf) {
                const int r = wn * 64 + nf * 16 + (lane & 15);
                b_[nf] = *(const bf16x8*)((const char*)Bs + r * 128 + ((cc ^ (r & 7)) << 4));
            }
            #pragma unroll
            for (int mf = 0; mf < 4; ++mf)
                #pragma unroll
                for (int nf = 0; nf < 4; ++nf)
                    acc[mf][nf] = __builtin_amdgcn_mfma_f32_16x16x32_bf16(
                        b_[nf], a_[mf], acc[mf][nf], 0, 0, 0);   // swapped -> Y^T frag
        }
        __syncthreads();
    }

    // Epilogue: Y = acc + s[t]*bias, float4 stores (Y^T frag: reg j = 4 cols).
    float sc4[2];
    #pragma unroll
    for (int tt = 0; tt < 2; ++tt) {
        const int t_ = ((row0 + wm * 64) >> 5) + tt;
        sc4[tt] = (1.0f - __expf(-2.3025851f * (float)(t_ + 1))) * ISCALE;
    }
    f32x4 bvv[4];
    #pragma unroll
    for (int nf = 0; nf < 4; ++nf)
        bvv[nf] = *(const f32x4*)(bias + col0 + wn * 64 + nf * 16 + ((lane >> 4) << 2));

    #pragma unroll
    for (int mf = 0; mf < 4; ++mf) {
        const int grow = row0 + wm * 64 + mf * 16 + (lane & 15);
        const float sc = sc4[mf >> 1];
        #pragma unroll
        for (int nf = 0; nf < 4; ++nf) {
            const int gcol = col0 + wn * 64 + nf * 16 + ((lane >> 4) << 2);
            f32x4 out;
            #pragma unroll
            for (int e = 0; e < 4; ++e) out[e] = acc[mf][nf][e] + sc * bvv[nf][e];
            *(f32x4*)(Y + (size_t)grow * O_DIM + gcol) = out;
        }
    }
}

extern "C" void kernel_launch(void* const* d_in, const int* in_sizes, int n_in,
                              void* d_out, int out_size, void* d_ws, size_t ws_size,
                              hipStream_t stream) {
    const float* X    = (const float*)d_in[0];
    const float* W    = (const float*)d_in[1];
    const float* bias = (const float*)d_in[2];
    float* Y = (float*)d_out;
    unsigned short* Wb = (unsigned short*)d_ws;                       // 512 KB
    unsigned short* Xv = (unsigned short*)((char*)d_ws + (1 << 20));  // 134 MB

    wcvt_kernel<<<dim3(O_DIM * I_DIM / (256 * 4)), dim3(256), 0, stream>>>(W, Wb);
    xema_kernel<<<dim3((T_DIM / STRIP) * 16), dim3(256), 0, stream>>>(X, Xv);
    gemm_kernel<<<dim3((M_DIM / BM) * (O_DIM / BN)), dim3(256), 0, stream>>>(Xv, Wb, bias, Y);
}